// Round 1
// baseline (4096.582 us; speedup 1.0000x reference)
//
#include <hip/hip_runtime.h>

// DQN landmark CNN: conv tower (shared weights, N=3072 images 4x45x45) + per-landmark FC heads.
// Round 0: fp32 VALU baseline, conv0+conv1 fused per image (h1 stays in LDS).

#define NIMG 3072

// ---- Kernel A: conv0(5x5,p1)+prelu+pool2 then conv1(5x5,p1)+prelu+pool2 ----
// x: (3072,4,45,45) -> h2: (3072,32,9,9)
__global__ __launch_bounds__(512) void k_conv01(
    const float* __restrict__ x,
    const float* __restrict__ w0, const float* __restrict__ b0, const float* __restrict__ a0p,
    const float* __restrict__ w1, const float* __restrict__ b1, const float* __restrict__ a1p,
    float* __restrict__ h2)
{
  // smem layout: phase 1: s_in [4][45][45] (8100) + s_h1 [16][22][22] padded (7744)
  //              phase 2 (reuse): s_c1 [32][18][18] raw conv1 (10368)
  __shared__ float smem[15844];   // 63,376 B
  float* s_in = smem;
  float* s_h1 = smem + 8100;
  float* s_c1 = smem;

  const int n = blockIdx.x;
  const int tid = threadIdx.x;
  const float a0 = a0p[0], a1 = a1p[0];

  // zero h1 pad region (row0/col0 stay zero through both phases) + load input
  for (int i = tid; i < 7744; i += 512) s_h1[i] = 0.f;
  const float* xin = x + n * 8100;
  for (int i = tid; i < 8100; i += 512) s_in[i] = xin[i];
  __syncthreads();

  // conv1 accumulators: thread -> co1 = tid/16, positions p = (tid%16) + 16j, 18x18 grid
  const int co1 = tid >> 4;
  const int pl  = tid & 15;
  int addr1[21];
  #pragma unroll
  for (int j = 0; j < 21; ++j) {
    int p = pl + j * 16;
    if (p < 324) { int y1 = p / 18, x1 = p % 18; addr1[j] = y1 * 22 + x1; }
    else addr1[j] = 0;   // dummy, contribution discarded
  }
  float acc[21];
  #pragma unroll
  for (int j = 0; j < 21; ++j) acc[j] = 0.f;

  for (int h = 0; h < 2; ++h) {
    if (h) __syncthreads();   // conv1 reads of s_h1 done before overwrite
    // ---- conv0+prelu+pool for out channels [16h,16h+16) -> s_h1 (padded +1,+1) ----
    for (int idx = tid; idx < 7056; idx += 512) {
      const int col = idx / 441;
      const int co  = h * 16 + col;
      const int p   = idx % 441;
      const int py  = p / 21, px = p % 21;
      const int r0 = 2 * py - 1, c0 = 2 * px - 1;
      float a00 = 0.f, a01 = 0.f, a10 = 0.f, a11 = 0.f;
      #pragma unroll
      for (int ci = 0; ci < 4; ++ci) {
        float win[36];
        const float* bp = s_in + ci * 2025 + r0 * 45 + c0;
        if (py > 0 && px > 0) {
          #pragma unroll
          for (int r = 0; r < 6; ++r)
            #pragma unroll
            for (int c = 0; c < 6; ++c) win[r*6+c] = bp[r*45+c];
        } else {
          #pragma unroll
          for (int r = 0; r < 6; ++r)
            #pragma unroll
            for (int c = 0; c < 6; ++c) {
              float v = 0.f;
              if ((r0 + r >= 0) && (c0 + c >= 0)) v = bp[r*45+c];
              win[r*6+c] = v;
            }
        }
        const float* wp = w0 + (co * 4 + ci) * 25;
        #pragma unroll
        for (int ky = 0; ky < 5; ++ky)
          #pragma unroll
          for (int kx = 0; kx < 5; ++kx) {
            const float w = wp[ky*5+kx];
            a00 += win[ky*6+kx]       * w;
            a01 += win[ky*6+kx+1]     * w;
            a10 += win[(ky+1)*6+kx]   * w;
            a11 += win[(ky+1)*6+kx+1] * w;
          }
      }
      float m = fmaxf(fmaxf(a00, a01), fmaxf(a10, a11)) + b0[co];
      s_h1[col * 484 + (py + 1) * 22 + (px + 1)] = (m >= 0.f) ? m : a0 * m;
    }
    __syncthreads();
    // ---- conv1 partial accumulation over ci in [16h,16h+16) ----
    for (int ci = 0; ci < 16; ++ci) {
      const float* wp = w1 + (co1 * 32 + h * 16 + ci) * 25;
      float wreg[25];
      #pragma unroll
      for (int t = 0; t < 25; ++t) wreg[t] = wp[t];
      const float* hb = s_h1 + ci * 484;
      #pragma unroll
      for (int j = 0; j < 21; ++j) {
        const float* q = hb + addr1[j];
        #pragma unroll
        for (int ky = 0; ky < 5; ++ky)
          #pragma unroll
          for (int kx = 0; kx < 5; ++kx)
            acc[j] += q[ky*22+kx] * wreg[ky*5+kx];
      }
    }
  }
  __syncthreads();
  // stash raw conv1 results (reuse smem)
  #pragma unroll
  for (int j = 0; j < 21; ++j) {
    int p = pl + j * 16;
    if (p < 324) s_c1[co1 * 324 + p] = acc[j];
  }
  __syncthreads();
  // pool + bias + prelu -> h2
  float* o = h2 + n * 2592;
  for (int idx = tid; idx < 2592; idx += 512) {
    int co = idx / 81, p = idx % 81, py = p / 9, px = p % 9;
    const float* c = s_c1 + co * 324 + (2*py) * 18 + 2*px;
    float m = fmaxf(fmaxf(c[0], c[1]), fmaxf(c[18], c[19])) + b1[co];
    o[idx] = (m >= 0.f) ? m : a1 * m;
  }
}

// ---- Kernel B: conv2(4x4,p1)+prelu+pool2 : h2(3072,32,9,9) -> h3(3072,64,4,4) ----
__global__ __launch_bounds__(256) void k_conv2(
    const float* __restrict__ h2, const float* __restrict__ w2,
    const float* __restrict__ b2, const float* __restrict__ a2p,
    float* __restrict__ h3)
{
  __shared__ float s2[3872];  // [32][11][11] zero-padded (+1,+1)
  const int n = blockIdx.x, tid = threadIdx.x;
  const float a2 = a2p[0];
  for (int i = tid; i < 3872; i += 256) s2[i] = 0.f;
  __syncthreads();
  const float* in = h2 + n * 2592;
  for (int i = tid; i < 2592; i += 256) {
    int ci = i / 81, r = (i % 81) / 9, c = i % 9;
    s2[ci * 121 + (r + 1) * 11 + (c + 1)] = in[i];
  }
  __syncthreads();
  float* o = h3 + n * 1024;
  for (int idx = tid; idx < 1024; idx += 256) {
    int co = idx >> 4, p = idx & 15, py = p >> 2, px = p & 3;
    float a00 = 0.f, a01 = 0.f, a10 = 0.f, a11 = 0.f;
    for (int ci = 0; ci < 32; ++ci) {
      float win[25];
      const float* bp = s2 + ci * 121 + (2*py) * 11 + (2*px);
      #pragma unroll
      for (int r = 0; r < 5; ++r)
        #pragma unroll
        for (int c = 0; c < 5; ++c) win[r*5+c] = bp[r*11+c];
      const float* wp = w2 + (co * 32 + ci) * 16;
      #pragma unroll
      for (int ky = 0; ky < 4; ++ky)
        #pragma unroll
        for (int kx = 0; kx < 4; ++kx) {
          float w = wp[ky*4+kx];
          a00 += win[ky*5+kx]       * w;
          a01 += win[ky*5+kx+1]     * w;
          a10 += win[(ky+1)*5+kx]   * w;
          a11 += win[(ky+1)*5+kx+1] * w;
        }
    }
    float m = fmaxf(fmaxf(a00, a01), fmaxf(a10, a11)) + b2[co];
    o[idx] = (m >= 0.f) ? m : a2 * m;
  }
}

// ---- Kernel C: conv3(3x3,p0)+prelu : h3(3072,64,4,4) -> h4(3072,256) ----
__global__ __launch_bounds__(256) void k_conv3(
    const float* __restrict__ h3, const float* __restrict__ w3,
    const float* __restrict__ b3, const float* __restrict__ a3p,
    float* __restrict__ h4)
{
  __shared__ float s3[1024];
  const int n = blockIdx.x, tid = threadIdx.x;
  const float a3 = a3p[0];
  for (int i = tid; i < 1024; i += 256) s3[i] = h3[n*1024 + i];
  __syncthreads();
  const int co = tid >> 2, p = tid & 3, oy = p >> 1, ox = p & 1;
  float acc = b3[co];
  for (int ci = 0; ci < 64; ++ci) {
    const float* bp = s3 + ci*16 + oy*4 + ox;
    const float* wp = w3 + (co*64 + ci)*9;
    #pragma unroll
    for (int ky = 0; ky < 3; ++ky)
      #pragma unroll
      for (int kx = 0; kx < 3; ++kx)
        acc += bp[ky*4+kx] * wp[ky*3+kx];
  }
  h4[n*256 + tid] = (acc >= 0.f) ? acc : a3 * acc;
}

// ---- Kernel D: per-landmark FC heads 256->128->64->4 ----
__global__ __launch_bounds__(128) void k_fc(
    const float* __restrict__ h4,
    const float* __restrict__ fc1w, const float* __restrict__ fc1b, const float* __restrict__ a4,
    const float* __restrict__ fc2w, const float* __restrict__ fc2b, const float* __restrict__ a5,
    const float* __restrict__ fc3w, const float* __restrict__ fc3b,
    float* __restrict__ out)
{
  __shared__ float sh[256 + 128 + 64];
  float* s0 = sh; float* s1 = sh + 256; float* sf2 = sh + 384;
  const int n = blockIdx.x, tid = threadIdx.x;
  const int l = n % 6;
  for (int i = tid; i < 256; i += 128) s0[i] = h4[n*256 + i];
  __syncthreads();
  {
    float acc = fc1b[l*128 + tid];
    const float* w = fc1w + l*32768 + tid;
    for (int i = 0; i < 256; ++i) acc += s0[i] * w[i*128];
    float a = a4[l];
    s1[tid] = (acc >= 0.f) ? acc : a * acc;
  }
  __syncthreads();
  if (tid < 64) {
    float acc = fc2b[l*64 + tid];
    const float* w = fc2w + l*8192 + tid;
    for (int i = 0; i < 128; ++i) acc += s1[i] * w[i*64];
    float a = a5[l];
    sf2[tid] = (acc >= 0.f) ? acc : a * acc;
  }
  __syncthreads();
  if (tid < 4) {
    float acc = fc3b[l*4 + tid];
    const float* w = fc3w + l*256 + tid;
    for (int i = 0; i < 64; ++i) acc += sf2[i] * w[i*4];
    out[n*4 + tid] = acc;
  }
}

extern "C" void kernel_launch(void* const* d_in, const int* in_sizes, int n_in,
                              void* d_out, int out_size, void* d_ws, size_t ws_size,
                              hipStream_t stream) {
  const float* x    = (const float*)d_in[0];
  const float* w0   = (const float*)d_in[1];
  const float* b0   = (const float*)d_in[2];
  const float* w1   = (const float*)d_in[3];
  const float* b1   = (const float*)d_in[4];
  const float* w2   = (const float*)d_in[5];
  const float* b2   = (const float*)d_in[6];
  const float* w3   = (const float*)d_in[7];
  const float* b3   = (const float*)d_in[8];
  const float* a0   = (const float*)d_in[9];
  const float* a1   = (const float*)d_in[10];
  const float* a2   = (const float*)d_in[11];
  const float* a3   = (const float*)d_in[12];
  const float* fc1w = (const float*)d_in[13];
  const float* fc1b = (const float*)d_in[14];
  const float* a4   = (const float*)d_in[15];
  const float* fc2w = (const float*)d_in[16];
  const float* fc2b = (const float*)d_in[17];
  const float* a5   = (const float*)d_in[18];
  const float* fc3w = (const float*)d_in[19];
  const float* fc3b = (const float*)d_in[20];
  float* out = (float*)d_out;

  char* ws = (char*)d_ws;
  float* h2 = (float*)(ws);               // 3072*32*9*9*4  = 31,850,496 B
  float* h3 = (float*)(ws + 31850496);    // 3072*64*4*4*4  = 12,582,912 B
  float* h4 = (float*)(ws + 44433408);    // 3072*256*4     =  3,145,728 B

  k_conv01<<<NIMG, 512, 0, stream>>>(x, w0, b0, a0, w1, b1, a1, h2);
  k_conv2 <<<NIMG, 256, 0, stream>>>(h2, w2, b2, a2, h3);
  k_conv3 <<<NIMG, 256, 0, stream>>>(h3, w3, b3, a3, h4);
  k_fc    <<<NIMG, 128, 0, stream>>>(h4, fc1w, fc1b, a4, fc2w, fc2b, a5, fc3w, fc3b, out);
}

// Round 2
// 403.718 us; speedup vs baseline: 10.1471x; 10.1471x over previous
//
#include <hip/hip_runtime.h>
#include <stdint.h>

typedef _Float16 f16;
typedef _Float16 half8 __attribute__((ext_vector_type(8)));
typedef _Float16 half4 __attribute__((ext_vector_type(4)));
typedef float floatx16 __attribute__((ext_vector_type(16)));

#define NIMG 3072

// ws byte offsets
#define WS_W0T 0            // f16 [5ky][2ch][2hf][32co][8j]   = 5120
#define WS_W1T 10240        // f16 [25tap][2ch][2hf][32co][8j] = 25600
#define WS_W2T 61440        // f16 [16tap][2ch][2ct][2hf][32co][8j] = 32768
#define WS_H2  131072       // f16 3072*81*32
#define WS_H3  16056320     // f32 3072*1024 (NCHW per image)
#define WS_H4  28639232     // f32 3072*256

// ---------------- weight transform ----------------
__global__ __launch_bounds__(256) void k_prep(
    const float* __restrict__ w0, const float* __restrict__ w1, const float* __restrict__ w2,
    f16* __restrict__ w0t, f16* __restrict__ w1t, f16* __restrict__ w2t)
{
  int stride = gridDim.x * blockDim.x;
  int g0 = blockIdx.x * blockDim.x + threadIdx.x;
  for (int i = g0; i < 5120; i += stride) {
    int j = i & 7, co = (i >> 3) & 31, hf = (i >> 8) & 1, ch = (i >> 9) & 1, ky = i >> 10;
    int k = ch * 16 + hf * 8 + j;
    f16 v = (f16)0.f;
    if (k < 20) { int kx = k >> 2, ci = k & 3; v = (f16)w0[((co * 4 + ci) * 5 + ky) * 5 + kx]; }
    w0t[i] = v;
  }
  for (int i = g0; i < 25600; i += stride) {
    int j = i & 7, co = (i >> 3) & 31, hf = (i >> 8) & 1, ch = (i >> 9) & 1, tap = i >> 10;
    int ci = ch * 16 + hf * 8 + j, ky = tap / 5, kx = tap % 5;
    w1t[i] = (f16)w1[((co * 32 + ci) * 5 + ky) * 5 + kx];
  }
  for (int i = g0; i < 32768; i += stride) {
    int j = i & 7, co = (i >> 3) & 31, hf = (i >> 8) & 1, ct = (i >> 9) & 1, ch = (i >> 10) & 1, tap = i >> 11;
    int ci = ch * 16 + hf * 8 + j, cog = ct * 32 + co, ky = tap >> 2, kx = tap & 3;
    w2t[i] = (f16)w2[((cog * 32 + ci) * 4 + ky) * 4 + kx];
  }
}

// ---------------- fused conv0+pool + conv1+pool (MFMA f16) ----------------
// x:(4,45,45)f32 per img -> h2g:(81pos,32co)f16 per img
__global__ __launch_bounds__(512) void k_conv01(
    const float* __restrict__ x,
    const f16* __restrict__ w0t, const float* __restrict__ b0, const float* __restrict__ a0p,
    const f16* __restrict__ w1t, const float* __restrict__ b1, const float* __restrict__ a1p,
    f16* __restrict__ h2g)
{
  __shared__ __align__(16) uint32_t smem_u[16328];   // 65,312 B
  f16* sh   = (f16*)smem_u;
  f16* s_x  = sh;           // [47][52][4]  = 9,776 f16 (input, +1 shift, zero pad)
  f16* s_h1 = sh + 9776;    // [22][26][40] = 22,880 f16 (h1 NHWC, +1 shift, ci-stride 40)

  const int n = blockIdx.x, tid = threadIdx.x;
  const int wv = tid >> 6, l = tid & 63;
  const int hf = l >> 5, m = l & 31, dr = m >> 3, dc = m & 7, col = m;
  const float a0 = a0p[0], a1 = a1p[0];
  const float b0c = b0[col], b1c = b1[col];
  const half8* w0t8 = (const half8*)w0t;
  const half8* w1t8 = (const half8*)w1t;

  for (int i = tid; i < 16328; i += 512) smem_u[i] = 0u;
  __syncthreads();
  const float* xin = x + n * 8100;
  for (int i = tid; i < 8100; i += 512) {
    int ci = i / 2025, r = i % 2025;
    int y = r / 45, xx = r % 45;
    s_x[((y + 1) * 52 + (xx + 1)) * 4 + ci] = (f16)xin[i];
  }
  __syncthreads();

  // ---- conv0: K per ky = kx(5)*ci(4)=20 padded to 32 (2 chunks of 16); B resident ----
  half8 B0[5][2];
  #pragma unroll
  for (int ky = 0; ky < 5; ++ky)
    #pragma unroll
    for (int ch = 0; ch < 2; ++ch)
      B0[ky][ch] = w0t8[(ky * 2 + ch) * 64 + hf * 32 + col];

  const int r0lut0[11] = {0,4,8,12,16,20,24,28,32,36,38};
  for (int t = wv; t < 66; t += 8) {
    int r0 = r0lut0[t / 6], cb = (t % 6) * 8;
    int rowb = r0 + dr, colb = cb + dc;
    const f16* pA0 = s_x + (rowb * 52 + colb + 2 * hf) * 4;  // chunk0: kx = 2hf,2hf+1
    const f16* pA1 = s_x + (rowb * 52 + colb + 4) * 4;       // chunk1: kx = 4 (hf==0 lanes)
    floatx16 acc = {0.f,0.f,0.f,0.f,0.f,0.f,0.f,0.f,0.f,0.f,0.f,0.f,0.f,0.f,0.f,0.f};
    #pragma unroll
    for (int ky = 0; ky < 5; ++ky) {
      half4 lo = *(const half4*)(pA0 + ky * 208);
      half4 hi = *(const half4*)(pA0 + ky * 208 + 4);
      half8 a0v = __builtin_shufflevector(lo, hi, 0,1,2,3,4,5,6,7);
      acc = __builtin_amdgcn_mfma_f32_32x32x16_f16(a0v, B0[ky][0], acc, 0, 0, 0);
      half8 a1v = {(f16)0,(f16)0,(f16)0,(f16)0,(f16)0,(f16)0,(f16)0,(f16)0};
      if (hf == 0) {
        half4 l1 = *(const half4*)(pA1 + ky * 208);
        a1v[0] = l1[0]; a1v[1] = l1[1]; a1v[2] = l1[2]; a1v[3] = l1[3];
      }
      acc = __builtin_amdgcn_mfma_f32_32x32x16_f16(a1v, B0[ky][1], acc, 0, 0, 0);
    }
    // pool 2x2 fully in-lane: reg i -> row (i>>2), col (i&3)+4*hf
    #pragma unroll
    for (int pp = 0; pp < 2; ++pp)
      #pragma unroll
      for (int c2 = 0; c2 < 2; ++c2) {
        float v = fmaxf(fmaxf(acc[8*pp + 2*c2], acc[8*pp + 2*c2 + 1]),
                        fmaxf(acc[8*pp + 4 + 2*c2], acc[8*pp + 4 + 2*c2 + 1]));
        v += b0c; v = (v >= 0.f) ? v : a0 * v;
        int pr = (r0 >> 1) + pp, pc = (cb >> 1) + 2 * hf + c2;
        if (pc < 21) s_h1[((pr + 1) * 26 + (pc + 1)) * 40 + col] = (f16)v;
      }
  }
  __syncthreads();

  // ---- conv1: 25 taps, K=32ci (2 chunks of 16); 15 tiles32, 2 per wave ----
  const int r0lut1[5] = {0, 4, 8, 12, 14};
  const int cclut[3]  = {0, 8, 14};
  int t0 = wv * 2;
  int t1 = t0 + 1; if (t1 > 14) t1 = 14;     // wave 7 duplicates tile 14 (benign)
  int r0a = r0lut1[t0 / 3], cca = cclut[t0 % 3];
  int r0b = r0lut1[t1 / 3], ccb = cclut[t1 % 3];
  const f16* pAa = s_h1 + ((r0a + dr) * 26 + cca + dc) * 40 + hf * 8;
  const f16* pAb = s_h1 + ((r0b + dr) * 26 + ccb + dc) * 40 + hf * 8;
  floatx16 accA = {0.f,0.f,0.f,0.f,0.f,0.f,0.f,0.f,0.f,0.f,0.f,0.f,0.f,0.f,0.f,0.f};
  floatx16 accB = {0.f,0.f,0.f,0.f,0.f,0.f,0.f,0.f,0.f,0.f,0.f,0.f,0.f,0.f,0.f,0.f};
  for (int ky = 0; ky < 5; ++ky) {
    const half8* wb = w1t8 + ky * 640 + hf * 32 + col;
    const f16* qa = pAa + ky * 1040;
    const f16* qb = pAb + ky * 1040;
    #pragma unroll
    for (int kx = 0; kx < 5; ++kx) {
      #pragma unroll
      for (int ch = 0; ch < 2; ++ch) {
        half8 b  = wb[kx * 128 + ch * 64];
        half8 aA = *(const half8*)(qa + kx * 40 + ch * 16);
        half8 aB = *(const half8*)(qb + kx * 40 + ch * 16);
        accA = __builtin_amdgcn_mfma_f32_32x32x16_f16(aA, b, accA, 0, 0, 0);
        accB = __builtin_amdgcn_mfma_f32_32x32x16_f16(aB, b, accB, 0, 0, 0);
      }
    }
  }
  f16* outp = h2g + n * 2592;
  #pragma unroll
  for (int tt = 0; tt < 2; ++tt) {
    const floatx16 acc = tt ? accB : accA;
    int r0 = tt ? r0b : r0a, cc = tt ? ccb : cca;
    #pragma unroll
    for (int pp = 0; pp < 2; ++pp)
      #pragma unroll
      for (int c2 = 0; c2 < 2; ++c2) {
        float v = fmaxf(fmaxf(acc[8*pp + 2*c2], acc[8*pp + 2*c2 + 1]),
                        fmaxf(acc[8*pp + 4 + 2*c2], acc[8*pp + 4 + 2*c2 + 1]));
        v += b1c; v = (v >= 0.f) ? v : a1 * v;
        int pr = (r0 >> 1) + pp, pc = (cc >> 1) + 2 * hf + c2;
        if (pc < 9) outp[(pr * 9 + pc) * 32 + col] = (f16)v;
      }
  }
}

// ---------------- conv2+pool (MFMA f16), 2 images per block ----------------
// h2g:(81,32)f16 -> h3:(64,4,4)f32 NCHW per image
__global__ __launch_bounds__(256) void k_conv2(
    const f16* __restrict__ h2g, const f16* __restrict__ w2t,
    const float* __restrict__ b2, const float* __restrict__ a2p,
    float* __restrict__ h3)
{
  __shared__ __align__(16) uint32_t s_u[5760];    // 2 imgs x [12][12][40] f16 = 23,040 B
  f16* s2 = (f16*)s_u;
  const int n0 = blockIdx.x * 2, tid = threadIdx.x;
  const int wv = tid >> 6, l = tid & 63;
  const int hf = l >> 5, m = l & 31, dr = m >> 3, dc = m & 7, col = m;
  const int img = wv >> 1, ct = wv & 1;
  const float a2 = a2p[0];
  const float b2c = b2[ct * 32 + col];
  const half8* w2t8 = (const half8*)w2t;

  for (int i = tid; i < 5760; i += 256) s_u[i] = 0u;
  __syncthreads();
  for (int c = tid; c < 648; c += 256) {
    int im = c / 324, rr = c % 324, pos = rr >> 2, part = rr & 3;
    int r = pos / 9, cc = pos % 9;
    *(half8*)(s2 + im * 5760 + ((r + 1) * 12 + (cc + 1)) * 40 + part * 8) =
      *(const half8*)(h2g + (n0 + im) * 2592 + pos * 32 + part * 8);
  }
  __syncthreads();

  const f16* sbase = s2 + img * 5760;
  const f16* pA0 = sbase + (dr * 12 + dc) * 40 + hf * 8;         // rows 0..3
  const f16* pA4 = sbase + ((4 + dr) * 12 + dc) * 40 + hf * 8;   // rows 4..7
  floatx16 acc0 = {0.f,0.f,0.f,0.f,0.f,0.f,0.f,0.f,0.f,0.f,0.f,0.f,0.f,0.f,0.f,0.f};
  floatx16 acc4 = {0.f,0.f,0.f,0.f,0.f,0.f,0.f,0.f,0.f,0.f,0.f,0.f,0.f,0.f,0.f,0.f};
  for (int tap = 0; tap < 16; ++tap) {
    int ky = tap >> 2, kx = tap & 3;
    int aoff = (ky * 12 + kx) * 40;
    #pragma unroll
    for (int ch = 0; ch < 2; ++ch) {
      half8 b  = w2t8[tap * 256 + ch * 128 + ct * 64 + hf * 32 + col];
      half8 a0 = *(const half8*)(pA0 + aoff + ch * 16);
      half8 a4 = *(const half8*)(pA4 + aoff + ch * 16);
      acc0 = __builtin_amdgcn_mfma_f32_32x32x16_f16(a0, b, acc0, 0, 0, 0);
      acc4 = __builtin_amdgcn_mfma_f32_32x32x16_f16(a4, b, acc4, 0, 0, 0);
    }
  }
  float* o = h3 + (n0 + img) * 1024;
  #pragma unroll
  for (int tt = 0; tt < 2; ++tt) {
    const floatx16 acc = tt ? acc4 : acc0;
    #pragma unroll
    for (int pp = 0; pp < 2; ++pp)
      #pragma unroll
      for (int c2 = 0; c2 < 2; ++c2) {
        float v = fmaxf(fmaxf(acc[8*pp + 2*c2], acc[8*pp + 2*c2 + 1]),
                        fmaxf(acc[8*pp + 4 + 2*c2], acc[8*pp + 4 + 2*c2 + 1]));
        v += b2c; v = (v >= 0.f) ? v : a2 * v;
        int pr = tt * 2 + pp, pc = 2 * hf + c2, co = ct * 32 + col;
        o[co * 16 + pr * 4 + pc] = v;
      }
  }
}

// ---------------- conv3 (fp32 VALU, unchanged) ----------------
__global__ __launch_bounds__(256) void k_conv3(
    const float* __restrict__ h3, const float* __restrict__ w3,
    const float* __restrict__ b3, const float* __restrict__ a3p,
    float* __restrict__ h4)
{
  __shared__ float s3[1024];
  const int n = blockIdx.x, tid = threadIdx.x;
  const float a3 = a3p[0];
  for (int i = tid; i < 1024; i += 256) s3[i] = h3[n*1024 + i];
  __syncthreads();
  const int co = tid >> 2, p = tid & 3, oy = p >> 1, ox = p & 1;
  float acc = b3[co];
  for (int ci = 0; ci < 64; ++ci) {
    const float* bp = s3 + ci*16 + oy*4 + ox;
    const float* wp = w3 + (co*64 + ci)*9;
    #pragma unroll
    for (int ky = 0; ky < 3; ++ky)
      #pragma unroll
      for (int kx = 0; kx < 3; ++kx)
        acc += bp[ky*4+kx] * wp[ky*3+kx];
  }
  h4[n*256 + tid] = (acc >= 0.f) ? acc : a3 * acc;
}

// ---------------- FC heads (fp32, unchanged) ----------------
__global__ __launch_bounds__(128) void k_fc(
    const float* __restrict__ h4,
    const float* __restrict__ fc1w, const float* __restrict__ fc1b, const float* __restrict__ a4,
    const float* __restrict__ fc2w, const float* __restrict__ fc2b, const float* __restrict__ a5,
    const float* __restrict__ fc3w, const float* __restrict__ fc3b,
    float* __restrict__ out)
{
  __shared__ float shm[256 + 128 + 64];
  float* s0 = shm; float* s1 = shm + 256; float* sf2 = shm + 384;
  const int n = blockIdx.x, tid = threadIdx.x;
  const int ll = n % 6;
  for (int i = tid; i < 256; i += 128) s0[i] = h4[n*256 + i];
  __syncthreads();
  {
    float acc = fc1b[ll*128 + tid];
    const float* w = fc1w + ll*32768 + tid;
    for (int i = 0; i < 256; ++i) acc += s0[i] * w[i*128];
    float a = a4[ll];
    s1[tid] = (acc >= 0.f) ? acc : a * acc;
  }
  __syncthreads();
  if (tid < 64) {
    float acc = fc2b[ll*64 + tid];
    const float* w = fc2w + ll*8192 + tid;
    for (int i = 0; i < 128; ++i) acc += s1[i] * w[i*64];
    float a = a5[ll];
    sf2[tid] = (acc >= 0.f) ? acc : a * acc;
  }
  __syncthreads();
  if (tid < 4) {
    float acc = fc3b[ll*4 + tid];
    const float* w = fc3w + ll*256 + tid;
    for (int i = 0; i < 64; ++i) acc += sf2[i] * w[i*4];
    out[n*4 + tid] = acc;
  }
}

extern "C" void kernel_launch(void* const* d_in, const int* in_sizes, int n_in,
                              void* d_out, int out_size, void* d_ws, size_t ws_size,
                              hipStream_t stream) {
  const float* x    = (const float*)d_in[0];
  const float* w0   = (const float*)d_in[1];
  const float* b0   = (const float*)d_in[2];
  const float* w1   = (const float*)d_in[3];
  const float* b1   = (const float*)d_in[4];
  const float* w2   = (const float*)d_in[5];
  const float* b2   = (const float*)d_in[6];
  const float* w3   = (const float*)d_in[7];
  const float* b3   = (const float*)d_in[8];
  const float* a0   = (const float*)d_in[9];
  const float* a1   = (const float*)d_in[10];
  const float* a2   = (const float*)d_in[11];
  const float* a3   = (const float*)d_in[12];
  const float* fc1w = (const float*)d_in[13];
  const float* fc1b = (const float*)d_in[14];
  const float* a4   = (const float*)d_in[15];
  const float* fc2w = (const float*)d_in[16];
  const float* fc2b = (const float*)d_in[17];
  const float* a5   = (const float*)d_in[18];
  const float* fc3w = (const float*)d_in[19];
  const float* fc3b = (const float*)d_in[20];
  float* out = (float*)d_out;

  char* ws = (char*)d_ws;
  f16*   w0t = (f16*)(ws + WS_W0T);
  f16*   w1t = (f16*)(ws + WS_W1T);
  f16*   w2t = (f16*)(ws + WS_W2T);
  f16*   h2g = (f16*)(ws + WS_H2);
  float* h3  = (float*)(ws + WS_H3);
  float* h4  = (float*)(ws + WS_H4);

  k_prep  <<<64, 256, 0, stream>>>(w0, w1, w2, w0t, w1t, w2t);
  k_conv01<<<NIMG, 512, 0, stream>>>(x, w0t, b0, a0, w1t, b1, a1, h2g);
  k_conv2 <<<NIMG/2, 256, 0, stream>>>(h2g, w2t, b2, a2, h3);
  k_conv3 <<<NIMG, 256, 0, stream>>>(h3, w3, b3, a3, h4);
  k_fc    <<<NIMG, 128, 0, stream>>>(h4, fc1w, fc1b, a4, fc2w, fc2b, a5, fc3w, fc3b, out);
}

// Round 3
// 336.491 us; speedup vs baseline: 12.1744x; 1.1998x over previous
//
#include <hip/hip_runtime.h>
#include <stdint.h>

typedef _Float16 f16;
typedef _Float16 half8 __attribute__((ext_vector_type(8)));
typedef _Float16 half4 __attribute__((ext_vector_type(4)));
typedef float floatx16 __attribute__((ext_vector_type(16)));

#define NIMG 3072

// ws byte offsets (all 16B-aligned)
#define WS_W0T   0           // f16 [5ky][2ch][2hf][32co][8j]            = 5,120
#define WS_W1T   10240       // f16 [25tap][2ch][2hf][32co][8j]          = 25,600
#define WS_W2T   61440       // f16 [16tap][2ch][2ct][2hf][32co][8j]     = 32,768
#define WS_W3T   126976      // f16 [36c][2ct][2hf][32col][8j]           = 36,864
#define WS_FC1T  200704      // f16 [6l][16c][4nt][2hf][32][8]           = 196,608
#define WS_FC2T  593920      // f16 [6l][8c][2nt][2hf][32][8]            = 49,152
#define WS_FC3T  692224      // f16 [6l][4c][2hf][32][8]                 = 12,288
#define WS_H2    720896      // f16 3072*81*32 (pos-major, 32co inner)
#define WS_H3F   16646144    // f16 3072*1024, NHWC [16pos][64ci]

#define Z16 {0.f,0.f,0.f,0.f,0.f,0.f,0.f,0.f,0.f,0.f,0.f,0.f,0.f,0.f,0.f,0.f}

// ---------------- weight transform ----------------
__global__ __launch_bounds__(256) void k_prep(
    const float* __restrict__ w0, const float* __restrict__ w1, const float* __restrict__ w2,
    const float* __restrict__ w3, const float* __restrict__ fc1w, const float* __restrict__ fc2w,
    const float* __restrict__ fc3w,
    f16* __restrict__ w0t, f16* __restrict__ w1t, f16* __restrict__ w2t, f16* __restrict__ w3t,
    f16* __restrict__ fc1t, f16* __restrict__ fc2t, f16* __restrict__ fc3t)
{
  int stride = gridDim.x * blockDim.x;
  int g0 = blockIdx.x * blockDim.x + threadIdx.x;
  for (int i = g0; i < 5120; i += stride) {
    int j = i & 7, co = (i >> 3) & 31, hf = (i >> 8) & 1, ch = (i >> 9) & 1, ky = i >> 10;
    int k = ch * 16 + hf * 8 + j;
    f16 v = (f16)0.f;
    if (k < 20) { int kx = k >> 2, ci = k & 3; v = (f16)w0[((co * 4 + ci) * 5 + ky) * 5 + kx]; }
    w0t[i] = v;
  }
  for (int i = g0; i < 25600; i += stride) {
    int j = i & 7, co = (i >> 3) & 31, hf = (i >> 8) & 1, ch = (i >> 9) & 1, tap = i >> 10;
    int ci = ch * 16 + hf * 8 + j, ky = tap / 5, kx = tap % 5;
    w1t[i] = (f16)w1[((co * 32 + ci) * 5 + ky) * 5 + kx];
  }
  for (int i = g0; i < 32768; i += stride) {
    int j = i & 7, co = (i >> 3) & 31, hf = (i >> 8) & 1, ct = (i >> 9) & 1, ch = (i >> 10) & 1, tap = i >> 11;
    int ci = ch * 16 + hf * 8 + j, cog = ct * 32 + co, ky = tap >> 2, kx = tap & 3;
    w2t[i] = (f16)w2[((cog * 32 + ci) * 4 + ky) * 4 + kx];
  }
  // conv3: K = tap*64 + ci (tap = ky*3+kx, 9 taps, 64 ci -> 576 = 36 chunks)
  for (int i = g0; i < 36864; i += stride) {
    int j = i & 7, col = (i >> 3) & 31, hf = (i >> 8) & 1, ct = (i >> 9) & 1, c = i >> 10;
    int k = c * 16 + hf * 8 + j, tap = k >> 6, ci = k & 63, co = ct * 32 + col;
    int ky = tap / 3, kx = tap % 3;
    w3t[i] = (f16)w3[((co * 64 + ci) * 3 + ky) * 3 + kx];
  }
  // fc1: (L,256,128)
  for (int i = g0; i < 196608; i += stride) {
    int j = i & 7, col = (i >> 3) & 31, hf = (i >> 8) & 1, nt = (i >> 9) & 3, c = (i >> 11) & 15, l = i >> 15;
    int k = c * 16 + hf * 8 + j, o = nt * 32 + col;
    fc1t[i] = (f16)fc1w[(l * 256 + k) * 128 + o];
  }
  // fc2: (L,128,64)
  for (int i = g0; i < 49152; i += stride) {
    int j = i & 7, col = (i >> 3) & 31, hf = (i >> 8) & 1, nt = (i >> 9) & 1, c = (i >> 10) & 7, l = i >> 13;
    int k = c * 16 + hf * 8 + j, o = nt * 32 + col;
    fc2t[i] = (f16)fc2w[(l * 128 + k) * 64 + o];
  }
  // fc3: (L,64,4), cols >=4 zero
  for (int i = g0; i < 12288; i += stride) {
    int j = i & 7, col = (i >> 3) & 31, hf = (i >> 8) & 1, c = (i >> 9) & 3, l = i >> 11;
    int k = c * 16 + hf * 8 + j;
    f16 v = (f16)0.f;
    if (col < 4) v = (f16)fc3w[(l * 64 + k) * 4 + col];
    fc3t[i] = v;
  }
}

// ---------------- fused conv0+pool + conv1+pool (MFMA f16) ----------------
__global__ __launch_bounds__(512) void k_conv01(
    const float* __restrict__ x,
    const f16* __restrict__ w0t, const float* __restrict__ b0, const float* __restrict__ a0p,
    const f16* __restrict__ w1t, const float* __restrict__ b1, const float* __restrict__ a1p,
    f16* __restrict__ h2g)
{
  __shared__ __align__(16) uint32_t smem_u[16328];   // 65,312 B
  f16* sh   = (f16*)smem_u;
  f16* s_x  = sh;           // [47][52][4]
  f16* s_h1 = sh + 9776;    // [22][26][40]

  const int n = blockIdx.x, tid = threadIdx.x;
  const int wv = tid >> 6, l = tid & 63;
  const int hf = l >> 5, m = l & 31, dr = m >> 3, dc = m & 7, col = m;
  const float a0 = a0p[0], a1 = a1p[0];
  const float b0c = b0[col], b1c = b1[col];
  const half8* w0t8 = (const half8*)w0t;
  const half8* w1t8 = (const half8*)w1t;

  for (int i = tid; i < 16328; i += 512) smem_u[i] = 0u;
  __syncthreads();
  const float* xin = x + n * 8100;
  for (int i = tid; i < 8100; i += 512) {
    int ci = i / 2025, r = i % 2025;
    int y = r / 45, xx = r % 45;
    s_x[((y + 1) * 52 + (xx + 1)) * 4 + ci] = (f16)xin[i];
  }
  __syncthreads();

  half8 B0[5][2];
  #pragma unroll
  for (int ky = 0; ky < 5; ++ky)
    #pragma unroll
    for (int ch = 0; ch < 2; ++ch)
      B0[ky][ch] = w0t8[(ky * 2 + ch) * 64 + hf * 32 + col];

  const int r0lut0[11] = {0,4,8,12,16,20,24,28,32,36,38};
  for (int t = wv; t < 66; t += 8) {
    int r0 = r0lut0[t / 6], cb = (t % 6) * 8;
    int rowb = r0 + dr, colb = cb + dc;
    const f16* pA0 = s_x + (rowb * 52 + colb + 2 * hf) * 4;
    const f16* pA1 = s_x + (rowb * 52 + colb + 4) * 4;
    floatx16 acc = Z16;
    #pragma unroll
    for (int ky = 0; ky < 5; ++ky) {
      half4 lo = *(const half4*)(pA0 + ky * 208);
      half4 hi = *(const half4*)(pA0 + ky * 208 + 4);
      half8 a0v = __builtin_shufflevector(lo, hi, 0,1,2,3,4,5,6,7);
      acc = __builtin_amdgcn_mfma_f32_32x32x16_f16(a0v, B0[ky][0], acc, 0, 0, 0);
      half8 a1v = {(f16)0,(f16)0,(f16)0,(f16)0,(f16)0,(f16)0,(f16)0,(f16)0};
      if (hf == 0) {
        half4 l1 = *(const half4*)(pA1 + ky * 208);
        a1v[0] = l1[0]; a1v[1] = l1[1]; a1v[2] = l1[2]; a1v[3] = l1[3];
      }
      acc = __builtin_amdgcn_mfma_f32_32x32x16_f16(a1v, B0[ky][1], acc, 0, 0, 0);
    }
    #pragma unroll
    for (int pp = 0; pp < 2; ++pp)
      #pragma unroll
      for (int c2 = 0; c2 < 2; ++c2) {
        float v = fmaxf(fmaxf(acc[8*pp + 2*c2], acc[8*pp + 2*c2 + 1]),
                        fmaxf(acc[8*pp + 4 + 2*c2], acc[8*pp + 4 + 2*c2 + 1]));
        v += b0c; v = (v >= 0.f) ? v : a0 * v;
        int pr = (r0 >> 1) + pp, pc = (cb >> 1) + 2 * hf + c2;
        if (pc < 21) s_h1[((pr + 1) * 26 + (pc + 1)) * 40 + col] = (f16)v;
      }
  }
  __syncthreads();

  const int r0lut1[5] = {0, 4, 8, 12, 14};
  const int cclut[3]  = {0, 8, 14};
  int t0 = wv * 2;
  int t1 = t0 + 1; if (t1 > 14) t1 = 14;
  int r0a = r0lut1[t0 / 3], cca = cclut[t0 % 3];
  int r0b = r0lut1[t1 / 3], ccb = cclut[t1 % 3];
  const f16* pAa = s_h1 + ((r0a + dr) * 26 + cca + dc) * 40 + hf * 8;
  const f16* pAb = s_h1 + ((r0b + dr) * 26 + ccb + dc) * 40 + hf * 8;
  floatx16 accA = Z16;
  floatx16 accB = Z16;
  for (int ky = 0; ky < 5; ++ky) {
    const half8* wb = w1t8 + ky * 640 + hf * 32 + col;
    const f16* qa = pAa + ky * 1040;
    const f16* qb = pAb + ky * 1040;
    #pragma unroll
    for (int kx = 0; kx < 5; ++kx) {
      #pragma unroll
      for (int ch = 0; ch < 2; ++ch) {
        half8 b  = wb[kx * 128 + ch * 64];
        half8 aA = *(const half8*)(qa + kx * 40 + ch * 16);
        half8 aB = *(const half8*)(qb + kx * 40 + ch * 16);
        accA = __builtin_amdgcn_mfma_f32_32x32x16_f16(aA, b, accA, 0, 0, 0);
        accB = __builtin_amdgcn_mfma_f32_32x32x16_f16(aB, b, accB, 0, 0, 0);
      }
    }
  }
  f16* outp = h2g + n * 2592;
  #pragma unroll
  for (int tt = 0; tt < 2; ++tt) {
    const floatx16 acc = tt ? accB : accA;
    int r0 = tt ? r0b : r0a, cc = tt ? ccb : cca;
    #pragma unroll
    for (int pp = 0; pp < 2; ++pp)
      #pragma unroll
      for (int c2 = 0; c2 < 2; ++c2) {
        float v = fmaxf(fmaxf(acc[8*pp + 2*c2], acc[8*pp + 2*c2 + 1]),
                        fmaxf(acc[8*pp + 4 + 2*c2], acc[8*pp + 4 + 2*c2 + 1]));
        v += b1c; v = (v >= 0.f) ? v : a1 * v;
        int pr = (r0 >> 1) + pp, pc = (cc >> 1) + 2 * hf + c2;
        if (pc < 9) outp[(pr * 9 + pc) * 32 + col] = (f16)v;
      }
  }
}

// ---------------- conv2+pool (MFMA f16), 2 images per block ----------------
// h2g:(81,32)f16 -> h3f:(16pos,64ci)f16 NHWC per image
__global__ __launch_bounds__(256) void k_conv2(
    const f16* __restrict__ h2g, const f16* __restrict__ w2t,
    const float* __restrict__ b2, const float* __restrict__ a2p,
    f16* __restrict__ h3f)
{
  __shared__ __align__(16) uint32_t s_u[5760];
  f16* s2 = (f16*)s_u;
  const int n0 = blockIdx.x * 2, tid = threadIdx.x;
  const int wv = tid >> 6, l = tid & 63;
  const int hf = l >> 5, m = l & 31, dr = m >> 3, dc = m & 7, col = m;
  const int img = wv >> 1, ct = wv & 1;
  const float a2 = a2p[0];
  const float b2c = b2[ct * 32 + col];
  const half8* w2t8 = (const half8*)w2t;

  for (int i = tid; i < 5760; i += 256) s_u[i] = 0u;
  __syncthreads();
  for (int c = tid; c < 648; c += 256) {
    int im = c / 324, rr = c % 324, pos = rr >> 2, part = rr & 3;
    int r = pos / 9, cc = pos % 9;
    *(half8*)(s2 + im * 5760 + ((r + 1) * 12 + (cc + 1)) * 40 + part * 8) =
      *(const half8*)(h2g + (n0 + im) * 2592 + pos * 32 + part * 8);
  }
  __syncthreads();

  const f16* sbase = s2 + img * 5760;
  const f16* pA0 = sbase + (dr * 12 + dc) * 40 + hf * 8;
  const f16* pA4 = sbase + ((4 + dr) * 12 + dc) * 40 + hf * 8;
  floatx16 acc0 = Z16;
  floatx16 acc4 = Z16;
  for (int tap = 0; tap < 16; ++tap) {
    int ky = tap >> 2, kx = tap & 3;
    int aoff = (ky * 12 + kx) * 40;
    #pragma unroll
    for (int ch = 0; ch < 2; ++ch) {
      half8 b  = w2t8[tap * 256 + ch * 128 + ct * 64 + hf * 32 + col];
      half8 a0 = *(const half8*)(pA0 + aoff + ch * 16);
      half8 a4 = *(const half8*)(pA4 + aoff + ch * 16);
      acc0 = __builtin_amdgcn_mfma_f32_32x32x16_f16(a0, b, acc0, 0, 0, 0);
      acc4 = __builtin_amdgcn_mfma_f32_32x32x16_f16(a4, b, acc4, 0, 0, 0);
    }
  }
  f16* o = h3f + (n0 + img) * 1024;
  #pragma unroll
  for (int tt = 0; tt < 2; ++tt) {
    const floatx16 acc = tt ? acc4 : acc0;
    #pragma unroll
    for (int pp = 0; pp < 2; ++pp)
      #pragma unroll
      for (int c2 = 0; c2 < 2; ++c2) {
        float v = fmaxf(fmaxf(acc[8*pp + 2*c2], acc[8*pp + 2*c2 + 1]),
                        fmaxf(acc[8*pp + 4 + 2*c2], acc[8*pp + 4 + 2*c2 + 1]));
        v += b2c; v = (v >= 0.f) ? v : a2 * v;
        int pr = tt * 2 + pp, pc = 2 * hf + c2, co = ct * 32 + col;
        o[(pr * 4 + pc) * 64 + co] = (f16)v;
      }
  }
}

// ---------------- fused conv3 + fc1 + fc2 + fc3 (MFMA f16) ----------------
// grid 96: blockIdx -> landmark l = b%6, image tile t = b/6 (32 images, n = (32t+i)*6+l)
__global__ __launch_bounds__(256) void k_tail(
    const f16* __restrict__ h3f,
    const f16* __restrict__ w3t, const float* __restrict__ b3, const float* __restrict__ a3p,
    const f16* __restrict__ fc1t, const float* __restrict__ fc1b, const float* __restrict__ a4,
    const f16* __restrict__ fc2t, const float* __restrict__ fc2b, const float* __restrict__ a5,
    const f16* __restrict__ fc3t, const float* __restrict__ fc3b,
    float* __restrict__ out)
{
  __shared__ __align__(16) f16 s_feat[32 * 264];  // row stride 264 f16 (528B: bank-start stride 4 -> b128 conflict-free)
  __shared__ __align__(16) f16 s_g1[32 * 136];
  __shared__ __align__(16) f16 s_g2[32 * 72];

  const int lm = blockIdx.x % 6, t = blockIdx.x / 6;
  const int tid = threadIdx.x, wv = tid >> 6, lane = tid & 63;
  const int hf = lane >> 5, col = lane & 31;
  const half8* w3t8  = (const half8*)w3t;
  const half8* fc1t8 = (const half8*)fc1t;
  const half8* fc2t8 = (const half8*)fc2t;
  const half8* fc3t8 = (const half8*)fc3t;

  // ---- conv3: wave = M-tile (8 images x 4 positions); K=576 (36 chunks); N=64 (2 ct) ----
  {
    const int mt = wv;
    const int i_img = mt * 8 + (col >> 2);
    const int pos = col & 3, oy = pos >> 1, ox = pos & 1;
    const int gimg = (t * 32 + i_img) * 6 + lm;
    const f16* Abase = h3f + gimg * 1024 + (oy * 4 + ox) * 64;
    floatx16 acc0 = Z16, acc1 = Z16;
    for (int c = 0; c < 36; ++c) {
      int tap = c >> 2;
      int ky = tap / 3, kx = tap % 3;
      half8 a = *(const half8*)(Abase + (ky * 4 + kx) * 64 + (c & 3) * 16 + hf * 8);
      half8 bb0 = w3t8[((c * 2 + 0) * 2 + hf) * 32 + col];
      half8 bb1 = w3t8[((c * 2 + 1) * 2 + hf) * 32 + col];
      acc0 = __builtin_amdgcn_mfma_f32_32x32x16_f16(a, bb0, acc0, 0, 0, 0);
      acc1 = __builtin_amdgcn_mfma_f32_32x32x16_f16(a, bb1, acc1, 0, 0, 0);
    }
    const float a3 = a3p[0];
    #pragma unroll
    for (int ct = 0; ct < 2; ++ct) {
      const floatx16 acc = ct ? acc1 : acc0;
      const int co = ct * 32 + col;
      const float bb = b3[co];
      #pragma unroll
      for (int q = 0; q < 4; ++q) {
        int ii = mt * 8 + 2 * q + hf;
        half4 w;
        #pragma unroll
        for (int z = 0; z < 4; ++z) {
          float v = acc[q * 4 + z] + bb;
          v = (v >= 0.f) ? v : a3 * v;
          w[z] = (f16)v;
        }
        *(half4*)(s_feat + ii * 264 + co * 4) = w;
      }
    }
  }
  __syncthreads();

  // ---- fc1: M=32 imgs, K=256 (16 chunks), N=128; wave = N-tile ----
  {
    floatx16 g = Z16;
    for (int c = 0; c < 16; ++c) {
      half8 a = *(const half8*)(s_feat + col * 264 + c * 16 + hf * 8);
      half8 b = fc1t8[(((lm * 16 + c) * 4 + wv) * 2 + hf) * 32 + col];
      g = __builtin_amdgcn_mfma_f32_32x32x16_f16(a, b, g, 0, 0, 0);
    }
    const float a4v = a4[lm];
    const float bb = fc1b[lm * 128 + wv * 32 + col];
    #pragma unroll
    for (int reg = 0; reg < 16; ++reg) {
      int r = (reg & 3) + 8 * (reg >> 2) + 4 * hf;
      float v = g[reg] + bb;
      v = (v >= 0.f) ? v : a4v * v;
      s_g1[r * 136 + wv * 32 + col] = (f16)v;
    }
  }
  __syncthreads();

  // ---- fc2: K=128 (8 chunks), N=64; waves 0,1 ----
  if (wv < 2) {
    floatx16 g = Z16;
    for (int c = 0; c < 8; ++c) {
      half8 a = *(const half8*)(s_g1 + col * 136 + c * 16 + hf * 8);
      half8 b = fc2t8[(((lm * 8 + c) * 2 + wv) * 2 + hf) * 32 + col];
      g = __builtin_amdgcn_mfma_f32_32x32x16_f16(a, b, g, 0, 0, 0);
    }
    const float a5v = a5[lm];
    const float bb = fc2b[lm * 64 + wv * 32 + col];
    #pragma unroll
    for (int reg = 0; reg < 16; ++reg) {
      int r = (reg & 3) + 8 * (reg >> 2) + 4 * hf;
      float v = g[reg] + bb;
      v = (v >= 0.f) ? v : a5v * v;
      s_g2[r * 72 + wv * 32 + col] = (f16)v;
    }
  }
  __syncthreads();

  // ---- fc3: K=64 (4 chunks), N=4 (padded); wave 0 ----
  if (wv == 0) {
    floatx16 g = Z16;
    for (int c = 0; c < 4; ++c) {
      half8 a = *(const half8*)(s_g2 + col * 72 + c * 16 + hf * 8);
      half8 b = fc3t8[((lm * 4 + c) * 2 + hf) * 32 + col];
      g = __builtin_amdgcn_mfma_f32_32x32x16_f16(a, b, g, 0, 0, 0);
    }
    if (col < 4) {
      const float bb = fc3b[lm * 4 + col];
      #pragma unroll
      for (int reg = 0; reg < 16; ++reg) {
        int r = (reg & 3) + 8 * (reg >> 2) + 4 * hf;
        out[((t * 32 + r) * 6 + lm) * 4 + col] = g[reg] + bb;
      }
    }
  }
}

extern "C" void kernel_launch(void* const* d_in, const int* in_sizes, int n_in,
                              void* d_out, int out_size, void* d_ws, size_t ws_size,
                              hipStream_t stream) {
  const float* x    = (const float*)d_in[0];
  const float* w0   = (const float*)d_in[1];
  const float* b0   = (const float*)d_in[2];
  const float* w1   = (const float*)d_in[3];
  const float* b1   = (const float*)d_in[4];
  const float* w2   = (const float*)d_in[5];
  const float* b2   = (const float*)d_in[6];
  const float* w3   = (const float*)d_in[7];
  const float* b3   = (const float*)d_in[8];
  const float* a0   = (const float*)d_in[9];
  const float* a1   = (const float*)d_in[10];
  const float* a2   = (const float*)d_in[11];
  const float* a3   = (const float*)d_in[12];
  const float* fc1w = (const float*)d_in[13];
  const float* fc1b = (const float*)d_in[14];
  const float* a4   = (const float*)d_in[15];
  const float* fc2w = (const float*)d_in[16];
  const float* fc2b = (const float*)d_in[17];
  const float* a5   = (const float*)d_in[18];
  const float* fc3w = (const float*)d_in[19];
  const float* fc3b = (const float*)d_in[20];
  float* out = (float*)d_out;

  char* ws = (char*)d_ws;
  f16* w0t  = (f16*)(ws + WS_W0T);
  f16* w1t  = (f16*)(ws + WS_W1T);
  f16* w2t  = (f16*)(ws + WS_W2T);
  f16* w3t  = (f16*)(ws + WS_W3T);
  f16* fc1t = (f16*)(ws + WS_FC1T);
  f16* fc2t = (f16*)(ws + WS_FC2T);
  f16* fc3t = (f16*)(ws + WS_FC3T);
  f16* h2g  = (f16*)(ws + WS_H2);
  f16* h3f  = (f16*)(ws + WS_H3F);

  k_prep  <<<128, 256, 0, stream>>>(w0, w1, w2, w3, fc1w, fc2w, fc3w,
                                    w0t, w1t, w2t, w3t, fc1t, fc2t, fc3t);
  k_conv01<<<NIMG, 512, 0, stream>>>(x, w0t, b0, a0, w1t, b1, a1, h2g);
  k_conv2 <<<NIMG/2, 256, 0, stream>>>(h2g, w2t, b2, a2, h3f);
  k_tail  <<<96, 256, 0, stream>>>(h3f, w3t, b3, a3, fc1t, fc1b, a4,
                                   fc2t, fc2b, a5, fc3t, fc3b, out);
}